// Round 2
// baseline (1291.967 us; speedup 1.0000x reference)
//
#include <hip/hip_runtime.h>
#include <hip/hip_bf16.h>

typedef _Float16 f16;
typedef _Float16 f16x8 __attribute__((ext_vector_type(8)));
typedef _Float16 f16x4 __attribute__((ext_vector_type(4)));
typedef float f32x4 __attribute__((ext_vector_type(4)));

#define TOKS 8192
#define DDIM 1024
#define CHDIM 256

// DAG edge tables (Watts-Strogatz ring lattice, M=16, k=4, min->max DAG).
// Edges flattened in node order; RJ = index into router_w[v,:npred] (sorted preds).
__device__ __constant__ int c_RV[32]   = {1, 2,2, 3,3, 4,4, 5,5, 6,6, 7,7, 8,8, 9,9, 10,10, 11,11, 12,12, 13,13, 14,14,14, 15,15,15,15};
__device__ __constant__ int c_RJ[32]   = {0, 0,1, 0,1, 0,1, 0,1, 0,1, 0,1, 0,1, 0,1, 0,1,   0,1,   0,1,   0,1,   0,1,2,    0,1,2,3};
// scratch slot of each predecessor: u==0->0, u==1->1, else 2+(u&1)
__device__ __constant__ int c_SLOT[32] = {0, 0,1, 1,2, 2,3, 3,2, 2,3, 3,2, 2,3, 3,2, 2,3,   3,2,   2,3,   3,2,   0,2,3,    0,1,3,2};
__device__ __constant__ int c_OFF[16]  = {0,0,1,3,5,7,9,11,13,15,17,19,21,23,25,28};
__device__ __constant__ int c_NP[16]   = {0,1,2,2,2,2,2,2,2,2,2,2,2,2,3,4};
__device__ __constant__ int c_WSLOT[16]= {0,1,2,3,2,3,2,3,2,3,2,3,2,3,2,0}; // node15 writes d_out instead

// ---------------- kernel 1: layernorm(x) -> f16 x_norm + router sigmoids (f32-exact) ----
// one wave per token; 4 tokens per block
__global__ __launch_bounds__(256) void k_lnx(const float* __restrict__ x, const float* __restrict__ g,
                                             const float* __restrict__ b, f16* __restrict__ xn,
                                             const float* __restrict__ rw, const float* __restrict__ rb,
                                             float* __restrict__ wsig){
  const int tid = threadIdx.x, lane = tid & 63, wv = tid >> 6;
  const int tk = blockIdx.x*4 + wv;
  const float* xp = x + (size_t)tk*DDIM + lane*16;
  float xv[16];
  #pragma unroll
  for (int j=0;j<16;j+=4){ const float4 f=*(const float4*)(xp+j); xv[j]=f.x; xv[j+1]=f.y; xv[j+2]=f.z; xv[j+3]=f.w; }
  float s=0.f, q=0.f;
  #pragma unroll
  for (int j=0;j<16;++j){ s += xv[j]; q += xv[j]*xv[j]; }
  #pragma unroll
  for (int m=1;m<64;m<<=1){ s += __shfl_xor(s,m); q += __shfl_xor(q,m); }
  const float mu = s*(1.f/DDIM);
  const float rs = rsqrtf(q*(1.f/DDIM) - mu*mu + 1e-5f);
  #pragma unroll
  for (int j=0;j<16;j+=4){
    const float4 gg=*(const float4*)(g + lane*16 + j);
    const float4 bb=*(const float4*)(b + lane*16 + j);
    xv[j]   = (xv[j]  -mu)*rs*gg.x + bb.x;
    xv[j+1] = (xv[j+1]-mu)*rs*gg.y + bb.y;
    xv[j+2] = (xv[j+2]-mu)*rs*gg.z + bb.z;
    xv[j+3] = (xv[j+3]-mu)*rs*gg.w + bb.w;
  }
  f16x8 o0, o1;
  #pragma unroll
  for (int j=0;j<8;++j){ o0[j] = (f16)xv[j]; o1[j] = (f16)xv[8+j]; }
  *(f16x8*)(xn + (size_t)tk*DDIM + lane*16)     = o0;
  *(f16x8*)(xn + (size_t)tk*DDIM + lane*16 + 8) = o1;
  // router sigmoids from exact f32 x_norm
  for (int e=0;e<32;++e){
    const int row = c_RV[e]*4 + c_RJ[e];
    const float* rp = rw + (size_t)row*DDIM + lane*16;
    float d = 0.f;
    #pragma unroll
    for (int j=0;j<16;j+=4){
      const float4 f=*(const float4*)(rp+j);
      d += xv[j]*f.x + xv[j+1]*f.y + xv[j+2]*f.z + xv[j+3]*f.w;
    }
    #pragma unroll
    for (int m=1;m<64;m<<=1) d += __shfl_xor(d,m);
    if (lane==0) wsig[tk*32 + e] = 1.f/(1.f + expf(-(d + rb[row])));
  }
}

// ---------------- kernel 2: fp32 weights -> f16 ----------------
__global__ __launch_bounds__(256) void k_cvt(const float* __restrict__ w1, const float* __restrict__ w2,
                                             f16* __restrict__ o1, f16* __restrict__ o2){
  const size_t i = ((size_t)blockIdx.x*256 + threadIdx.x)*4;
  const float4 a = *(const float4*)(w1+i);
  f16x4 r; r[0]=(f16)a.x; r[1]=(f16)a.y; r[2]=(f16)a.z; r[3]=(f16)a.w;
  *(f16x4*)(o1+i) = r;
  const float4 c = *(const float4*)(w2+i);
  f16x4 t; t[0]=(f16)c.x; t[1]=(f16)c.y; t[2]=(f16)c.z; t[3]=(f16)c.w;
  *(f16x4*)(o2+i) = t;
}

// ---------------- kernel 3: fused persistent MoE-DAG ----------------
// grid 256 blocks x 256 threads; block owns 32 tokens through all 16 nodes.
// No inter-block deps -> no grid sync. Scratch `outs` is block-private.
__global__ __launch_bounds__(256,1) void k_moe(
    const f16* __restrict__ xn, const f16* __restrict__ w1h, const f16* __restrict__ w2h,
    const float* __restrict__ fc1b, const float* __restrict__ lng, const float* __restrict__ lnb,
    const float* __restrict__ f2bias, const float* __restrict__ wsigG,
    const float* __restrict__ x, float* __restrict__ out, f16* __restrict__ outs)
{
  __shared__ float wsig[32][32];                            // [token][edge] router sigmoids
  __shared__ __align__(16) f16 Alds[2*32*72];               // dbuf node_in tile [32][64], row pad 72
  __shared__ __align__(16) f16 hln[32*264];                 // LN'd hidden [32][256], row pad 264
  __shared__ float part[32][2][2];                          // per-token LN partials

  const int tid = threadIdx.x;
  const int lane = tid & 63, wv = tid >> 6;
  const int l15 = lane & 15, g4 = lane >> 4;
  const int mw = wv >> 1, nw = wv & 1;      // 2x2 wave grid
  const int blk = blockIdx.x;
  const int tok0 = blk * 32;

  // load this block's router sigmoids (32 tokens x 32 edges = 4KB)
  {
    const float4 wv4 = *(const float4*)(wsigG + tok0*32 + tid*4);
    *(float4*)&wsig[(tid*4)>>5][(tid*4)&31] = wv4;
  }
  __syncthreads();

  const int st = tid >> 3, ss = tid & 7;   // staging: token, 8-elem slot

  for (int v=0; v<16; ++v){
    const int np = c_NP[v], off = c_OFF[v];
    const f16* pb[4]; float wgt[4];
    #pragma unroll
    for (int p=0;p<4;++p){
      const int e = off + (p<np ? p : 0);
      pb[p] = outs + (size_t)(c_SLOT[e]*256 + blk)*32*DDIM + (size_t)st*DDIM;
      wgt[p] = (p<np) ? wsig[st][e] : 0.f;
    }
    const f16* W1v = w1h + (size_t)v*CHDIM*DDIM;   // [256][1024] row-major (N x K)
    const f16* W2v = w2h + (size_t)v*DDIM*CHDIM;   // [1024][256] row-major (N x K)

    // build node_in chunk [32 x 64] in f16 into Alds
    auto stageA = [&](int ic){
      const int k0 = ic*64 + ss*8;
      f16x8 val;
      if (v==0){
        val = *(const f16x8*)(xn + (size_t)(tok0+st)*DDIM + k0);
      } else {
        float f[8];
        #pragma unroll
        for (int j=0;j<8;++j) f[j]=0.f;
        #pragma unroll
        for (int p=0;p<4;++p) if (p<np){
          const f16x8 o = *(const f16x8*)(pb[p] + k0);
          #pragma unroll
          for (int j=0;j<8;++j) f[j] += wgt[p]*(float)o[j];
        }
        #pragma unroll
        for (int j=0;j<8;++j) val[j] = (f16)f[j];
      }
      *(f16x8*)&Alds[(ic&1)*2304 + st*72 + ss*8] = val;
    };

    // ---- fc1: [32 x 1024] x [1024 x 256] -> 32x256, K-chunks of 64, A dbuf in LDS, B global->reg ----
    const f32x4 fzero = {0.f,0.f,0.f,0.f};
    f32x4 acc1[8];
    #pragma unroll
    for (int i=0;i<8;++i) acc1[i] = fzero;

    stageA(0);

    for (int ic=0; ic<16; ++ic){
      __syncthreads();
      f16x8 bfr[8][2];
      #pragma unroll
      for (int nf=0;nf<8;++nf){
        const f16* bp = W1v + (size_t)(nw*128 + nf*16 + l15)*DDIM + ic*64 + g4*8;
        bfr[nf][0] = *(const f16x8*)(bp);
        bfr[nf][1] = *(const f16x8*)(bp + 32);
      }
      if (ic < 15) stageA(ic+1);          // staging VALU/loads hide B latency
      const int ar = mw*16 + l15;
      f16x8 af[2];
      #pragma unroll
      for (int ks=0;ks<2;++ks)
        af[ks] = *(const f16x8*)&Alds[(ic&1)*2304 + ar*72 + (ks*4+g4)*8];
      #pragma unroll
      for (int ks=0;ks<2;++ks)
        #pragma unroll
        for (int nf=0;nf<8;++nf)
          acc1[nf] = __builtin_amdgcn_mfma_f32_16x16x32_f16(af[ks], bfr[nf][ks], acc1[nf], 0,0,0);
    }

    // ---- fc1 epilogue: bias + exact gelu + LN(256) ----
    const int cb = nw*128 + l15;
    float fbv[8], lgv[8], lbv[8];
    #pragma unroll
    for (int nf=0;nf<8;++nf){
      const int c = cb + nf*16;
      fbv[nf] = fc1b[v*CHDIM + c];
      lgv[nf] = lng[v*CHDIM + c];
      lbv[nf] = lnb[v*CHDIM + c];
    }
    #pragma unroll
    for (int nf=0;nf<8;++nf)
      #pragma unroll
      for (int r=0;r<4;++r){
        const float h = acc1[nf][r] + fbv[nf];
        acc1[nf][r] = 0.5f*h*(1.f + erff(h*0.70710678118654752f));
      }
    #pragma unroll
    for (int r=0;r<4;++r){
      float s=0.f, q=0.f;
      #pragma unroll
      for (int nf=0;nf<8;++nf){ const float h = acc1[nf][r]; s += h; q += h*h; }
      #pragma unroll
      for (int m=1;m<16;m<<=1){ s += __shfl_xor(s,m); q += __shfl_xor(q,m); }
      if (l15==0){
        const int t = mw*16 + g4*4 + r;
        part[t][nw][0]=s; part[t][nw][1]=q;
      }
    }
    __syncthreads();
    float muv[4], rsv[4];
    #pragma unroll
    for (int r=0;r<4;++r){
      const int t = mw*16 + g4*4 + r;
      const float s = part[t][0][0] + part[t][1][0];
      const float q = part[t][0][1] + part[t][1][1];
      muv[r] = s*(1.f/CHDIM);
      rsv[r] = rsqrtf(q*(1.f/CHDIM) - muv[r]*muv[r] + 1e-5f);
    }
    #pragma unroll
    for (int nf=0;nf<8;++nf)
      #pragma unroll
      for (int r=0;r<4;++r){
        const int t = mw*16 + g4*4 + r;
        hln[t*264 + cb + nf*16] = (f16)((acc1[nf][r]-muv[r])*rsv[r]*lgv[nf] + lbv[nf]);
      }
    __syncthreads();

    // ---- fc2: [32 x 256] x [256 x 1024], A from LDS, B global->reg (ping-pong over K) ----
    for (int pass=0; pass<4; ++pass){
      const int nb = nw*512 + pass*128;
      f32x4 acc2[8];
      #pragma unroll
      for (int i=0;i<8;++i) acc2[i] = fzero;
      f16x8 bb[2][8];
      #pragma unroll
      for (int nf=0;nf<8;++nf)
        bb[0][nf] = *(const f16x8*)(W2v + (size_t)(nb + nf*16 + l15)*CHDIM + g4*8);
      const int ar2 = mw*16 + l15;
      #pragma unroll
      for (int ks=0;ks<8;++ks){
        if (ks<7){
          #pragma unroll
          for (int nf=0;nf<8;++nf)
            bb[(ks+1)&1][nf] = *(const f16x8*)(W2v + (size_t)(nb + nf*16 + l15)*CHDIM + (ks+1)*32 + g4*8);
        }
        const f16x8 a = *(const f16x8*)&hln[ar2*264 + ks*32 + g4*8];
        #pragma unroll
        for (int nf=0;nf<8;++nf)
          acc2[nf] = __builtin_amdgcn_mfma_f32_16x16x32_f16(a, bb[ks&1][nf], acc2[nf], 0,0,0);
      }
      if (v < 15){
        f16* wo = outs + (size_t)(c_WSLOT[v]*256 + blk)*32*DDIM;
        #pragma unroll
        for (int nf=0;nf<8;++nf)
          #pragma unroll
          for (int r=0;r<4;++r){
            const int t = mw*16 + g4*4 + r;
            wo[(size_t)t*DDIM + nb + nf*16 + l15] = (f16)acc2[nf][r];
          }
      } else {
        #pragma unroll
        for (int nf=0;nf<8;++nf){
          const int c = nb + nf*16 + l15;
          const float fb = f2bias[c];
          #pragma unroll
          for (int r=0;r<4;++r){
            const int t = mw*16 + g4*4 + r;
            const size_t gidx = (size_t)(tok0+t)*DDIM + c;
            out[gidx] = x[gidx] + acc2[nf][r] + fb;   // residual + terminal bias
          }
        }
      }
    }
    __syncthreads();   // outs stores visible before next node's staging reads
  }
}

extern "C" void kernel_launch(void* const* d_in, const int* in_sizes, int n_in,
                              void* d_out, int out_size, void* d_ws, size_t ws_size,
                              hipStream_t stream) {
  (void)in_sizes; (void)n_in; (void)out_size; (void)ws_size;
  const float* x   = (const float*)d_in[0];
  const float* ng  = (const float*)d_in[1];
  const float* nb_ = (const float*)d_in[2];
  const float* w1  = (const float*)d_in[3];
  const float* f1b = (const float*)d_in[4];
  const float* lg  = (const float*)d_in[5];
  const float* lb  = (const float*)d_in[6];
  const float* w2  = (const float*)d_in[7];
  const float* f2b = (const float*)d_in[8];
  const float* rw  = (const float*)d_in[9];
  const float* rb  = (const float*)d_in[10];
  float* out = (float*)d_out;

  char* ws = (char*)d_ws;
  f16*  xnh  = (f16*)(ws);                                   // 16,777,216 B
  f16*  w1h  = (f16*)(ws + 16777216);                        //  8,388,608 B
  f16*  w2h  = (f16*)(ws + 16777216 + 8388608);              //  8,388,608 B
  float* wsg = (float*)(ws + 16777216 + 8388608 + 8388608);  //  1,048,576 B
  f16*  outs = (f16*)(ws + 16777216 + 8388608 + 8388608 + 1048576); // 67,108,864 B (4 slots)

  k_lnx<<<TOKS/4, 256, 0, stream>>>(x, ng, nb_, xnh, rw, rb, wsg);
  k_cvt<<<4096, 256, 0, stream>>>(w1, w2, w1h, w2h);
  k_moe<<<256, 256, 0, stream>>>(xnh, w1h, w2h, f1b, lg, lb, f2b, wsg, x, out, outs);
}

// Round 3
// 692.506 us; speedup vs baseline: 1.8656x; 1.8656x over previous
//
#include <hip/hip_runtime.h>
#include <hip/hip_bf16.h>

typedef _Float16 f16;
typedef _Float16 f16x8 __attribute__((ext_vector_type(8)));
typedef _Float16 f16x4 __attribute__((ext_vector_type(4)));
typedef float f32x4 __attribute__((ext_vector_type(4)));

#define TOKS 8192
#define DDIM 1024
#define CHDIM 256

// DAG tables (Watts-Strogatz ring, M=16, k=4, min->max DAG). Edges flat in node order.
__device__ __constant__ int c_PRED[32] = {0, 0,1, 1,2, 2,3, 3,4, 4,5, 5,6, 6,7, 7,8, 8,9, 9,10, 10,11, 11,12, 0,12,13, 0,1,13,14};
__device__ __constant__ int c_SLOT[32] = {0, 0,1, 1,2, 2,3, 3,2, 2,3, 3,2, 2,3, 3,2, 2,3,   3,2,   2,3,   3,2,   0,2,3,    0,1,3,2};
__device__ __constant__ int c_OFF[16]  = {0,0,1,3,5,7,9,11,13,15,17,19,21,23,25,28};
__device__ __constant__ int c_NP[16]   = {0,1,2,2,2,2,2,2,2,2,2,2,2,2,3,4};
__device__ __constant__ int c_WSLOT[16]= {0,1,2,3,2,3,2,3,2,3,2,3,2,3,2,0};
// router-weight row per edge = RV*4 + RJ
__device__ __constant__ int c_RROW[32] = {4, 8,9, 12,13, 16,17, 20,21, 24,25, 28,29, 32,33, 36,37, 40,41, 44,45, 48,49, 52,53, 56,57,58, 60,61,62,63};

// ---------------- kernel 1: layernorm(x) -> f16 x_norm + router sigmoids (f32-exact) ----
__global__ __launch_bounds__(256) void k_lnx(const float* __restrict__ x, const float* __restrict__ g,
                                             const float* __restrict__ b, f16* __restrict__ xn,
                                             const float* __restrict__ rw, const float* __restrict__ rb,
                                             float* __restrict__ wsig){
  const int tid = threadIdx.x, lane = tid & 63, wv = tid >> 6;
  const int tk = blockIdx.x*4 + wv;
  const float* xp = x + (size_t)tk*DDIM + lane*16;
  float xv[16];
  #pragma unroll
  for (int j=0;j<16;j+=4){ const float4 f=*(const float4*)(xp+j); xv[j]=f.x; xv[j+1]=f.y; xv[j+2]=f.z; xv[j+3]=f.w; }
  float s=0.f, q=0.f;
  #pragma unroll
  for (int j=0;j<16;++j){ s += xv[j]; q += xv[j]*xv[j]; }
  #pragma unroll
  for (int m=1;m<64;m<<=1){ s += __shfl_xor(s,m); q += __shfl_xor(q,m); }
  const float mu = s*(1.f/DDIM);
  const float rs = rsqrtf(q*(1.f/DDIM) - mu*mu + 1e-5f);
  #pragma unroll
  for (int j=0;j<16;j+=4){
    const float4 gg=*(const float4*)(g + lane*16 + j);
    const float4 bb=*(const float4*)(b + lane*16 + j);
    xv[j]   = (xv[j]  -mu)*rs*gg.x + bb.x;
    xv[j+1] = (xv[j+1]-mu)*rs*gg.y + bb.y;
    xv[j+2] = (xv[j+2]-mu)*rs*gg.z + bb.z;
    xv[j+3] = (xv[j+3]-mu)*rs*gg.w + bb.w;
  }
  f16x8 o0, o1;
  #pragma unroll
  for (int j=0;j<8;++j){ o0[j] = (f16)xv[j]; o1[j] = (f16)xv[8+j]; }
  *(f16x8*)(xn + (size_t)tk*DDIM + lane*16)     = o0;
  *(f16x8*)(xn + (size_t)tk*DDIM + lane*16 + 8) = o1;
  for (int e=0;e<32;++e){
    const int row = c_RROW[e];
    const float* rp = rw + (size_t)row*DDIM + lane*16;
    float d = 0.f;
    #pragma unroll
    for (int j=0;j<16;j+=4){
      const float4 f=*(const float4*)(rp+j);
      d += xv[j]*f.x + xv[j+1]*f.y + xv[j+2]*f.z + xv[j+3]*f.w;
    }
    #pragma unroll
    for (int m=1;m<64;m<<=1) d += __shfl_xor(d,m);
    if (lane==0) wsig[tk*32 + e] = 1.f/(1.f + expf(-(d + rb[row])));
  }
}

// ---------------- kernel 2: fp32 weights -> f16 ----------------
__global__ __launch_bounds__(256) void k_cvt(const float* __restrict__ w1, const float* __restrict__ w2,
                                             f16* __restrict__ o1, f16* __restrict__ o2){
  const size_t i = ((size_t)blockIdx.x*256 + threadIdx.x)*4;
  const float4 a = *(const float4*)(w1+i);
  f16x4 r; r[0]=(f16)a.x; r[1]=(f16)a.y; r[2]=(f16)a.z; r[3]=(f16)a.w;
  *(f16x4*)(o1+i) = r;
  const float4 c = *(const float4*)(w2+i);
  f16x4 t; t[0]=(f16)c.x; t[1]=(f16)c.y; t[2]=(f16)c.z; t[3]=(f16)c.w;
  *(f16x4*)(o2+i) = t;
}

// ---------------- kernel 3: fused persistent MoE-DAG ----------------
// 256 blocks x 1024 threads (16 waves). Block owns 32 tokens through all 16 nodes.
// Full node-input tile [32][1024] f16 lives in LDS -> fc1 K-loop is barrier-free.
// Wave grid 1M x 16N: each weight byte loaded once per block.
__global__ __launch_bounds__(1024,4) void k_moe(
    const f16* __restrict__ xn, const f16* __restrict__ w1h, const f16* __restrict__ w2h,
    const float* __restrict__ fc1b, const float* __restrict__ lng, const float* __restrict__ lnb,
    const float* __restrict__ f2bias, const float* __restrict__ wsigG,
    const float* __restrict__ x, float* __restrict__ out, f16* __restrict__ outs)
{
  __shared__ float wsig[32][32];                 // router sigmoids [token][edge]
  __shared__ __align__(16) f16 Ain[32*1032];     // node-in tile [32][1024] pad->1032 (also fc2-out bounce)
  __shared__ __align__(16) f16 hln[32*264];      // LN'd hidden [32][256] pad->264
  __shared__ float part[32][17][2];              // per-token LN partials (pad 17 breaks bank aliasing)
  __shared__ float musq[32][2];                  // per-token {mu, rsqrt}

  const int tid = threadIdx.x;
  const int lane = tid & 63, wv = tid >> 6;      // wv 0..15
  const int l15 = lane & 15, g4 = (lane >> 4) & 3;
  const int blk = blockIdx.x, tok0 = blk * 32;
  const f32x4 fzero = {0.f,0.f,0.f,0.f};

  wsig[tid>>5][tid&31] = wsigG[tok0*32 + tid];
  // initial stage: Ain = x_norm tile (node 0 input)
  #pragma unroll
  for (int p=0;p<4;++p){
    const int c = tid + p*1024, row = c>>7, cc = c&127;
    *(f16x8*)&Ain[row*1032 + cc*8] = *(const f16x8*)(xn + (size_t)(tok0+row)*DDIM + cc*8);
  }
  __syncthreads();

  for (int v=0; v<16; ++v){
    // ---- fc1: [32x1024]x[1024x256] ; wave = 16 cols, both M-frags ; NO barriers ----
    const f16* W1v = w1h + (size_t)v*CHDIM*DDIM;
    const f16* bp1 = W1v + (size_t)(wv*16 + l15)*DDIM + g4*8;
    f32x4 acc1[2] = {fzero, fzero};
    #pragma unroll 4
    for (int ic=0; ic<32; ++ic){
      const f16x8 b  = *(const f16x8*)(bp1 + ic*32);
      const f16x8 a0 = *(const f16x8*)&Ain[l15*1032      + ic*32 + g4*8];
      const f16x8 a1 = *(const f16x8*)&Ain[(16+l15)*1032 + ic*32 + g4*8];
      acc1[0] = __builtin_amdgcn_mfma_f32_16x16x32_f16(a0, b, acc1[0], 0,0,0);
      acc1[1] = __builtin_amdgcn_mfma_f32_16x16x32_f16(a1, b, acc1[1], 0,0,0);
    }

    // ---- epilogue: bias + exact gelu + LN(256) ----
    const int c1 = wv*16 + l15;
    const float fb = fc1b[v*CHDIM + c1];
    const float lg = lng[v*CHDIM + c1], lb = lnb[v*CHDIM + c1];
    #pragma unroll
    for (int mf=0;mf<2;++mf)
      #pragma unroll
      for (int r=0;r<4;++r){
        const float h = acc1[mf][r] + fb;
        acc1[mf][r] = 0.5f*h*(1.f + erff(h*0.70710678118654752f));
      }
    #pragma unroll
    for (int mf=0;mf<2;++mf)
      #pragma unroll
      for (int r=0;r<4;++r){
        float s = acc1[mf][r], q = s*s;
        #pragma unroll
        for (int m=1;m<16;m<<=1){ s += __shfl_xor(s,m); q += __shfl_xor(q,m); }
        if (l15==0){ const int t = mf*16 + g4*4 + r; part[t][wv][0]=s; part[t][wv][1]=q; }
      }
    __syncthreads();
    if (tid < 32){
      float s=0.f, q=0.f;
      #pragma unroll
      for (int w=0;w<16;++w){ s += part[tid][w][0]; q += part[tid][w][1]; }
      const float mu = s*(1.f/CHDIM);
      musq[tid][0] = mu;
      musq[tid][1] = rsqrtf(q*(1.f/CHDIM) - mu*mu + 1e-5f);
    }
    __syncthreads();
    #pragma unroll
    for (int mf=0;mf<2;++mf)
      #pragma unroll
      for (int r=0;r<4;++r){
        const int t = mf*16 + g4*4 + r;
        hln[t*264 + c1] = (f16)((acc1[mf][r]-musq[t][0])*musq[t][1]*lg + lb);
      }
    __syncthreads();

    // ---- fc2: [32x256]x[256x1024] ; wave = 64 cols (4 N-frags), both M-frags ; NO barriers ----
    const f16* W2v = w2h + (size_t)v*DDIM*CHDIM;
    f32x4 acc2[2][4];
    #pragma unroll
    for (int mf=0;mf<2;++mf)
      #pragma unroll
      for (int nf=0;nf<4;++nf) acc2[mf][nf] = fzero;
    #pragma unroll 2
    for (int ks=0; ks<8; ++ks){
      const f16x8 a0 = *(const f16x8*)&hln[l15*264      + ks*32 + g4*8];
      const f16x8 a1 = *(const f16x8*)&hln[(16+l15)*264 + ks*32 + g4*8];
      #pragma unroll
      for (int nf=0;nf<4;++nf){
        const f16x8 b = *(const f16x8*)(W2v + (size_t)(wv*64 + nf*16 + l15)*CHDIM + ks*32 + g4*8);
        acc2[0][nf] = __builtin_amdgcn_mfma_f32_16x16x32_f16(a0, b, acc2[0][nf], 0,0,0);
        acc2[1][nf] = __builtin_amdgcn_mfma_f32_16x16x32_f16(a1, b, acc2[1][nf], 0,0,0);
      }
    }
    // bounce fc2 output into Ain (dead after fc1) for coalesced flush; +bias on terminal node
    #pragma unroll
    for (int mf=0;mf<2;++mf)
      #pragma unroll
      for (int nf=0;nf<4;++nf){
        const int c2 = wv*64 + nf*16 + l15;
        const float fb2 = (v==15) ? f2bias[c2] : 0.f;
        #pragma unroll
        for (int r=0;r<4;++r){
          const int t = mf*16 + g4*4 + r;
          Ain[t*1032 + c2] = (f16)(acc2[mf][nf][r] + fb2);
        }
      }
    __syncthreads();

    // ---- flush node output + stage next node input (fused, same-thread chunks) ----
    if (v < 15){
      f16* wo = outs + (size_t)(c_WSLOT[v]*256 + blk)*32*DDIM;
      const int w = v+1, np2 = c_NP[w], off2 = c_OFF[w];
      #pragma unroll
      for (int p=0;p<4;++p){
        const int c = tid + p*1024, row = c>>7, cc = c&127;
        const f16x8 val = *(const f16x8*)&Ain[row*1032 + cc*8];
        if (v <= 13) *(f16x8*)(wo + (size_t)row*DDIM + cc*8) = val;  // node14 output only consumed via LDS
        float f[8];
        #pragma unroll
        for (int j=0;j<8;++j) f[j]=0.f;
        for (int p2=0; p2<np2; ++p2){
          const int e = off2 + p2, u = c_PRED[e];
          const float wg = wsig[row][e];
          f16x8 o;
          if (u == v) o = val;
          else o = *(const f16x8*)(outs + (size_t)(c_SLOT[e]*256 + blk)*32*DDIM + (size_t)row*DDIM + cc*8);
          #pragma unroll
          for (int j=0;j<8;++j) f[j] += wg*(float)o[j];
        }
        f16x8 nv;
        #pragma unroll
        for (int j=0;j<8;++j) nv[j] = (f16)f[j];
        *(f16x8*)&Ain[row*1032 + cc*8] = nv;
      }
      __syncthreads();
    } else {
      // terminal: out = x + (fc2_out + fc2_bias), coalesced
      #pragma unroll
      for (int p=0;p<4;++p){
        const int c = tid + p*1024, row = c>>7, cc = c&127;
        const f16x8 val = *(const f16x8*)&Ain[row*1032 + cc*8];
        const size_t gi = (size_t)(tok0+row)*DDIM + cc*8;
        const float4 x0 = *(const float4*)(x+gi), x1 = *(const float4*)(x+gi+4);
        float4 o0, o1;
        o0.x = x0.x + (float)val[0]; o0.y = x0.y + (float)val[1];
        o0.z = x0.z + (float)val[2]; o0.w = x0.w + (float)val[3];
        o1.x = x1.x + (float)val[4]; o1.y = x1.y + (float)val[5];
        o1.z = x1.z + (float)val[6]; o1.w = x1.w + (float)val[7];
        *(float4*)(out+gi) = o0; *(float4*)(out+gi+4) = o1;
      }
    }
  }
}

extern "C" void kernel_launch(void* const* d_in, const int* in_sizes, int n_in,
                              void* d_out, int out_size, void* d_ws, size_t ws_size,
                              hipStream_t stream) {
  (void)in_sizes; (void)n_in; (void)out_size; (void)ws_size;
  const float* x   = (const float*)d_in[0];
  const float* ng  = (const float*)d_in[1];
  const float* nb_ = (const float*)d_in[2];
  const float* w1  = (const float*)d_in[3];
  const float* f1b = (const float*)d_in[4];
  const float* lg  = (const float*)d_in[5];
  const float* lb  = (const float*)d_in[6];
  const float* w2  = (const float*)d_in[7];
  const float* f2b = (const float*)d_in[8];
  const float* rw  = (const float*)d_in[9];
  const float* rb  = (const float*)d_in[10];
  float* out = (float*)d_out;

  char* ws = (char*)d_ws;
  f16*  xnh  = (f16*)(ws);                                   // 16 MB
  f16*  w1h  = (f16*)(ws + 16777216);                        //  8 MB
  f16*  w2h  = (f16*)(ws + 16777216 + 8388608);              //  8 MB
  float* wsg = (float*)(ws + 16777216 + 8388608 + 8388608);  //  1 MB
  f16*  outs = (f16*)(ws + 16777216 + 8388608 + 8388608 + 1048576); // 64 MB (4 slots)

  k_lnx<<<TOKS/4, 256, 0, stream>>>(x, ng, nb_, xnh, rw, rb, wsg);
  k_cvt<<<4096, 256, 0, stream>>>(w1, w2, w1h, w2h);
  k_moe<<<256, 1024, 0, stream>>>(xnh, w1h, w2h, f1b, lg, lb, f2b, wsg, x, out, outs);
}

// Round 4
// 556.881 us; speedup vs baseline: 2.3200x; 1.2435x over previous
//
#include <hip/hip_runtime.h>
#include <hip/hip_bf16.h>

typedef _Float16 f16;
typedef _Float16 f16x8 __attribute__((ext_vector_type(8)));
typedef float f32x4 __attribute__((ext_vector_type(4)));

#define TOKS 8192
#define DDIM 1024
#define CHDIM 256

// DAG tables (Watts-Strogatz ring, M=16, k=4, min->max DAG). Edges flat in node order.
// Preds are sorted ascending; the chain pred (v = w-1) is ALWAYS the last edge of node w.
__device__ __constant__ int c_PRED[32] = {0, 0,1, 1,2, 2,3, 3,4, 4,5, 5,6, 6,7, 7,8, 8,9, 9,10, 10,11, 11,12, 0,12,13, 0,1,13,14};
__device__ __constant__ int c_SLOT[32] = {0, 0,1, 1,2, 2,3, 3,2, 2,3, 3,2, 2,3, 3,2, 2,3,   3,2,   2,3,   3,2,   0,2,3,    0,1,3,2};
__device__ __constant__ int c_OFF[16]  = {0,0,1,3,5,7,9,11,13,15,17,19,21,23,25,28};
__device__ __constant__ int c_NP[16]   = {0,1,2,2,2,2,2,2,2,2,2,2,2,2,3,4};
__device__ __constant__ int c_WSLOT[16]= {0,1,2,3,2,3,2,3,2,3,2,3,2,3,2,0};
__device__ __constant__ int c_RROW[32] = {4, 8,9, 12,13, 16,17, 20,21, 24,25, 28,29, 32,33, 36,37, 40,41, 44,45, 48,49, 52,53, 56,57,58, 60,61,62,63};

// ---------------- kernel 1: prep (merged) ----------------
// blocks 0..2047:    layernorm(x)->f16 xn + router sigmoids (f32-exact), 4 tokens/block
// blocks 2048..4095: pack W1 fp32 -> f16 fragment-ordered
// blocks 4096..6143: pack W2 fp32 -> f16 fragment-ordered
__global__ __launch_bounds__(256) void k_prep(const float* __restrict__ x, const float* __restrict__ g,
                                              const float* __restrict__ b, f16* __restrict__ xn,
                                              const float* __restrict__ rw, const float* __restrict__ rb,
                                              float* __restrict__ wsig,
                                              const float* __restrict__ w1, const float* __restrict__ w2,
                                              f16* __restrict__ w1p, f16* __restrict__ w2p){
  const int blk = blockIdx.x, tid = threadIdx.x;
  if (blk < 2048){
    const int lane = tid & 63, wv = tid >> 6;
    const int tk = blk*4 + wv;
    const float* xp = x + (size_t)tk*DDIM + lane*16;
    float xv[16];
    #pragma unroll
    for (int j=0;j<16;j+=4){ const float4 f=*(const float4*)(xp+j); xv[j]=f.x; xv[j+1]=f.y; xv[j+2]=f.z; xv[j+3]=f.w; }
    float s=0.f, q=0.f;
    #pragma unroll
    for (int j=0;j<16;++j){ s += xv[j]; q += xv[j]*xv[j]; }
    #pragma unroll
    for (int m=1;m<64;m<<=1){ s += __shfl_xor(s,m); q += __shfl_xor(q,m); }
    const float mu = s*(1.f/DDIM);
    const float rs = rsqrtf(q*(1.f/DDIM) - mu*mu + 1e-5f);
    #pragma unroll
    for (int j=0;j<16;j+=4){
      const float4 gg=*(const float4*)(g + lane*16 + j);
      const float4 bb=*(const float4*)(b + lane*16 + j);
      xv[j]   = (xv[j]  -mu)*rs*gg.x + bb.x;
      xv[j+1] = (xv[j+1]-mu)*rs*gg.y + bb.y;
      xv[j+2] = (xv[j+2]-mu)*rs*gg.z + bb.z;
      xv[j+3] = (xv[j+3]-mu)*rs*gg.w + bb.w;
    }
    f16x8 o0, o1;
    #pragma unroll
    for (int j=0;j<8;++j){ o0[j] = (f16)xv[j]; o1[j] = (f16)xv[8+j]; }
    *(f16x8*)(xn + (size_t)tk*DDIM + lane*16)     = o0;
    *(f16x8*)(xn + (size_t)tk*DDIM + lane*16 + 8) = o1;
    for (int e=0;e<32;++e){
      const int row = c_RROW[e];
      const float* rp = rw + (size_t)row*DDIM + lane*16;
      float d = 0.f;
      #pragma unroll
      for (int j=0;j<16;j+=4){
        const float4 f=*(const float4*)(rp+j);
        d += xv[j]*f.x + xv[j+1]*f.y + xv[j+2]*f.z + xv[j+3]*f.w;
      }
      #pragma unroll
      for (int m=1;m<64;m<<=1) d += __shfl_xor(d,m);
      if (lane==0) wsig[tk*32 + e] = 1.f/(1.f + expf(-(d + rb[row])));
    }
  } else if (blk < 4096){
    // W1 pack: c = v*32768 + wv*2048 + ic*64 + g4*16 + l15 ; dst chunk c*8
    const int c = (blk-2048)*256 + tid;
    const int l15 = c & 15, g4 = (c>>4)&3, ic = (c>>6)&31, wvv = (c>>11)&15, v = c>>15;
    const float* s = w1 + (size_t)v*262144 + (size_t)(wvv*16+l15)*1024 + ic*32 + g4*8;
    const float4 a = *(const float4*)s, b4 = *(const float4*)(s+4);
    f16x8 o;
    o[0]=(f16)a.x; o[1]=(f16)a.y; o[2]=(f16)a.z; o[3]=(f16)a.w;
    o[4]=(f16)b4.x; o[5]=(f16)b4.y; o[6]=(f16)b4.z; o[7]=(f16)b4.w;
    *(f16x8*)(w1p + (size_t)c*8) = o;
  } else {
    // W2 pack: c = v*32768 + wv*2048 + ks*256 + nf*64 + g4*16 + l15 ; dst chunk c*8
    const int c = (blk-4096)*256 + tid;
    const int l15 = c & 15, g4 = (c>>4)&3, nf = (c>>6)&3, ks = (c>>8)&7, wvv = (c>>11)&15, v = c>>15;
    const float* s = w2 + (size_t)v*262144 + (size_t)(wvv*64+nf*16+l15)*256 + ks*32 + g4*8;
    const float4 a = *(const float4*)s, b4 = *(const float4*)(s+4);
    f16x8 o;
    o[0]=(f16)a.x; o[1]=(f16)a.y; o[2]=(f16)a.z; o[3]=(f16)a.w;
    o[4]=(f16)b4.x; o[5]=(f16)b4.y; o[6]=(f16)b4.z; o[7]=(f16)b4.w;
    *(f16x8*)(w2p + (size_t)c*8) = o;
  }
}

// ---------------- kernel 2: fused persistent MoE-DAG ----------------
// 256 blocks x 1024 threads (16 waves, 1 block/CU). Block owns 32 tokens, all 16 nodes.
// Weights pre-packed per-wave-fragment-contiguous -> all weight loads fully coalesced.
__global__ __launch_bounds__(1024,4) void k_moe(
    const f16* __restrict__ xn, const f16* __restrict__ w1p, const f16* __restrict__ w2p,
    const float* __restrict__ fc1b, const float* __restrict__ lng, const float* __restrict__ lnb,
    const float* __restrict__ f2bias, const float* __restrict__ wsigG,
    const float* __restrict__ x, float* __restrict__ out, f16* __restrict__ outs)
{
  __shared__ float wsig[32][32];                 // router sigmoids [token][edge]
  __shared__ __align__(16) f16 Ain[32*1032];     // node-in tile [32][1024] pad->1032 (also fc2-out bounce)
  __shared__ __align__(16) f16 hln[32*264];      // LN'd hidden [32][256] pad->264
  __shared__ float part[32][17][2];              // per-token LN partials
  __shared__ float musq[32][2];                  // per-token {mu, rsqrt}

  const int tid = threadIdx.x;
  const int lane = tid & 63, wv = tid >> 6;      // wv 0..15
  const int l15 = lane & 15, g4 = (lane >> 4) & 3;
  const int blk = blockIdx.x, tok0 = blk * 32;
  const f32x4 fzero = {0.f,0.f,0.f,0.f};

  wsig[tid>>5][tid&31] = wsigG[tok0*32 + tid];
  #pragma unroll
  for (int p=0;p<4;++p){
    const int c = tid + p*1024, row = c>>7, cc = c&127;
    *(f16x8*)&Ain[row*1032 + cc*8] = *(const f16x8*)(xn + (size_t)(tok0+row)*DDIM + cc*8);
  }
  __syncthreads();

  for (int v=0; v<16; ++v){
    // ---- fc1: [32x1024]x[1024x256] ; wave = 16 cols, both M-frags ; barrier-free ----
    const f16* bp1 = w1p + (size_t)(v*16 + wv)*16384 + lane*8;   // contiguous 1KB per ic
    f32x4 acc1[2] = {fzero, fzero};
    #pragma unroll 4
    for (int ic=0; ic<32; ++ic){
      const f16x8 b  = *(const f16x8*)(bp1 + ic*512);
      const f16x8 a0 = *(const f16x8*)&Ain[l15*1032      + ic*32 + g4*8];
      const f16x8 a1 = *(const f16x8*)&Ain[(16+l15)*1032 + ic*32 + g4*8];
      acc1[0] = __builtin_amdgcn_mfma_f32_16x16x32_f16(a0, b, acc1[0], 0,0,0);
      acc1[1] = __builtin_amdgcn_mfma_f32_16x16x32_f16(a1, b, acc1[1], 0,0,0);
    }

    // ---- epilogue: bias + exact gelu + LN(256) ----
    const int c1 = wv*16 + l15;
    const float fb = fc1b[v*CHDIM + c1];
    const float lg = lng[v*CHDIM + c1], lb = lnb[v*CHDIM + c1];
    #pragma unroll
    for (int mf=0;mf<2;++mf)
      #pragma unroll
      for (int r=0;r<4;++r){
        const float h = acc1[mf][r] + fb;
        acc1[mf][r] = 0.5f*h*(1.f + erff(h*0.70710678118654752f));
      }
    #pragma unroll
    for (int mf=0;mf<2;++mf)
      #pragma unroll
      for (int r=0;r<4;++r){
        float s = acc1[mf][r], q = s*s;
        #pragma unroll
        for (int m=1;m<16;m<<=1){ s += __shfl_xor(s,m); q += __shfl_xor(q,m); }
        if (l15==0){ const int t = mf*16 + g4*4 + r; part[t][wv][0]=s; part[t][wv][1]=q; }
      }
    __syncthreads();
    if (tid < 32){
      float s=0.f, q=0.f;
      #pragma unroll
      for (int w=0;w<16;++w){ s += part[tid][w][0]; q += part[tid][w][1]; }
      const float mu = s*(1.f/CHDIM);
      musq[tid][0] = mu;
      musq[tid][1] = rsqrtf(q*(1.f/CHDIM) - mu*mu + 1e-5f);
    }
    __syncthreads();
    #pragma unroll
    for (int mf=0;mf<2;++mf)
      #pragma unroll
      for (int r=0;r<4;++r){
        const int t = mf*16 + g4*4 + r;
        hln[t*264 + c1] = (f16)((acc1[mf][r]-musq[t][0])*musq[t][1]*lg + lb);
      }
    __syncthreads();

    // ---- fc2: [32x256]x[256x1024] ; wave = 64 cols (4 N-frags), both M-frags ; barrier-free ----
    const f16* bp2 = w2p + (size_t)(v*16 + wv)*16384 + lane*8;   // + ks*2048 + nf*512
    f32x4 acc2[2][4];
    #pragma unroll
    for (int mf=0;mf<2;++mf)
      #pragma unroll
      for (int nf=0;nf<4;++nf) acc2[mf][nf] = fzero;
    #pragma unroll 2
    for (int ks=0; ks<8; ++ks){
      const f16x8 a0 = *(const f16x8*)&hln[l15*264      + ks*32 + g4*8];
      const f16x8 a1 = *(const f16x8*)&hln[(16+l15)*264 + ks*32 + g4*8];
      #pragma unroll
      for (int nf=0;nf<4;++nf){
        const f16x8 b = *(const f16x8*)(bp2 + ks*2048 + nf*512);
        acc2[0][nf] = __builtin_amdgcn_mfma_f32_16x16x32_f16(a0, b, acc2[0][nf], 0,0,0);
        acc2[1][nf] = __builtin_amdgcn_mfma_f32_16x16x32_f16(a1, b, acc2[1][nf], 0,0,0);
      }
    }
    // bounce fc2 output into Ain (dead after fc1); +terminal bias
    #pragma unroll
    for (int mf=0;mf<2;++mf)
      #pragma unroll
      for (int nf=0;nf<4;++nf){
        const int c2 = wv*64 + nf*16 + l15;
        const float fb2 = (v==15) ? f2bias[c2] : 0.f;
        #pragma unroll
        for (int r=0;r<4;++r){
          const int t = mf*16 + g4*4 + r;
          Ain[t*1032 + c2] = (f16)(acc2[mf][nf][r] + fb2);
        }
      }
    __syncthreads();

    // ---- flush node output + stage next node input (loads hoisted before stores) ----
    if (v < 15){
      f16* wo = outs + (size_t)(c_WSLOT[v]*256 + blk)*32*DDIM;
      const int w = v+1, np2 = c_NP[w], off2 = c_OFF[w];
      const int ne = np2 - 1, evi = off2 + ne;   // chain pred (==v) is always last edge
      f16x8 val[4], po[2][4];
      #pragma unroll
      for (int p=0;p<4;++p){
        const int cch = tid + p*1024, row = cch>>7, cc = cch&127;
        val[p] = *(const f16x8*)&Ain[row*1032 + cc*8];
        #pragma unroll
        for (int i=0;i<2;++i) if (i<ne){
          const int e = off2 + i;
          po[i][p] = *(const f16x8*)(outs + (size_t)(c_SLOT[e]*256+blk)*32*DDIM + (size_t)row*DDIM + cc*8);
        }
      }
      if (v <= 13){
        #pragma unroll
        for (int p=0;p<4;++p){
          const int cch = tid + p*1024, row = cch>>7, cc = cch&127;
          *(f16x8*)(wo + (size_t)row*DDIM + cc*8) = val[p];
        }
      }
      #pragma unroll
      for (int p=0;p<4;++p){
        const int cch = tid + p*1024, row = cch>>7, cc = cch&127;
        float f[8];
        const float wgv = wsig[row][evi];
        #pragma unroll
        for (int j=0;j<8;++j) f[j] = wgv*(float)val[p][j];
        #pragma unroll
        for (int i=0;i<2;++i) if (i<ne){
          const float wg = wsig[row][off2+i];
          #pragma unroll
          for (int j=0;j<8;++j) f[j] += wg*(float)po[i][p][j];
        }
        if (ne > 2){  // only node 15 (3rd non-chain pred), load inline
          const int e = off2 + 2;
          const f16x8 o = *(const f16x8*)(outs + (size_t)(c_SLOT[e]*256+blk)*32*DDIM + (size_t)row*DDIM + cc*8);
          const float wg = wsig[row][e];
          #pragma unroll
          for (int j=0;j<8;++j) f[j] += wg*(float)o[j];
        }
        f16x8 nv;
        #pragma unroll
        for (int j=0;j<8;++j) nv[j] = (f16)f[j];
        *(f16x8*)&Ain[row*1032 + cc*8] = nv;
      }
      __syncthreads();
    } else {
      // terminal: out = x + (fc2_out + fc2_bias)
      #pragma unroll
      for (int p=0;p<4;++p){
        const int c = tid + p*1024, row = c>>7, cc = c&127;
        const f16x8 val2 = *(const f16x8*)&Ain[row*1032 + cc*8];
        const size_t gi = (size_t)(tok0+row)*DDIM + cc*8;
        const float4 x0 = *(const float4*)(x+gi), x1 = *(const float4*)(x+gi+4);
        float4 o0, o1;
        o0.x = x0.x + (float)val2[0]; o0.y = x0.y + (float)val2[1];
        o0.z = x0.z + (float)val2[2]; o0.w = x0.w + (float)val2[3];
        o1.x = x1.x + (float)val2[4]; o1.y = x1.y + (float)val2[5];
        o1.z = x1.z + (float)val2[6]; o1.w = x1.w + (float)val2[7];
        *(float4*)(out+gi) = o0; *(float4*)(out+gi+4) = o1;
      }
    }
  }
}

extern "C" void kernel_launch(void* const* d_in, const int* in_sizes, int n_in,
                              void* d_out, int out_size, void* d_ws, size_t ws_size,
                              hipStream_t stream) {
  (void)in_sizes; (void)n_in; (void)out_size; (void)ws_size;
  const float* x   = (const float*)d_in[0];
  const float* ng  = (const float*)d_in[1];
  const float* nb_ = (const float*)d_in[2];
  const float* w1  = (const float*)d_in[3];
  const float* f1b = (const float*)d_in[4];
  const float* lg  = (const float*)d_in[5];
  const float* lb  = (const float*)d_in[6];
  const float* w2  = (const float*)d_in[7];
  const float* f2b = (const float*)d_in[8];
  const float* rw  = (const float*)d_in[9];
  const float* rb  = (const float*)d_in[10];
  float* out = (float*)d_out;

  char* ws = (char*)d_ws;
  f16*  xnh  = (f16*)(ws);                                   // 16 MB
  f16*  w1p  = (f16*)(ws + 16777216);                        //  8 MB
  f16*  w2p  = (f16*)(ws + 16777216 + 8388608);              //  8 MB
  float* wsg = (float*)(ws + 16777216 + 8388608 + 8388608);  //  1 MB
  f16*  outs = (f16*)(ws + 16777216 + 8388608 + 8388608 + 1048576); // 64 MB (4 slots)

  k_prep<<<6144, 256, 0, stream>>>(x, ng, nb_, xnh, rw, rb, wsg, w1, w2, w1p, w2p);
  k_moe<<<256, 1024, 0, stream>>>(xnh, w1p, w2p, f1b, lg, lb, f2b, wsg, x, out, outs);
}

// Round 5
// 508.734 us; speedup vs baseline: 2.5396x; 1.0946x over previous
//
#include <hip/hip_runtime.h>
#include <hip/hip_bf16.h>

typedef _Float16 f16;
typedef _Float16 f16x8 __attribute__((ext_vector_type(8)));
typedef float f32x4 __attribute__((ext_vector_type(4)));

#define TOKS 8192
#define DDIM 1024
#define CHDIM 256

// DAG: preds(v) ⊆ {v-1, v-2, 0, 1}. Edge order (sorted preds): extras first, then v-2, then v-1.
__device__ __constant__ int c_OFF[16]  = {0,0,1,3,5,7,9,11,13,15,17,19,21,23,25,28};
__device__ __constant__ int c_NP[16]   = {0,1,2,2,2,2,2,2,2,2,2,2,2,2,3,4};
__device__ __constant__ int c_RROW[32] = {4, 8,9, 12,13, 16,17, 20,21, 24,25, 28,29, 32,33, 36,37, 40,41, 44,45, 48,49, 52,53, 56,57,58, 60,61,62,63};

// ---------------- kernel 1: prep (merged) ----------------
// blocks 0..2047: LN(x)->f16 xn + router sigmoids (f32-exact). 2048..4095: pack W1. 4096..6143: pack W2.
__global__ __launch_bounds__(256) void k_prep(const float* __restrict__ x, const float* __restrict__ g,
                                              const float* __restrict__ b, f16* __restrict__ xn,
                                              const float* __restrict__ rw, const float* __restrict__ rb,
                                              float* __restrict__ wsig,
                                              const float* __restrict__ w1, const float* __restrict__ w2,
                                              f16* __restrict__ w1p, f16* __restrict__ w2p){
  const int blk = blockIdx.x, tid = threadIdx.x;
  if (blk < 2048){
    const int lane = tid & 63, wv = tid >> 6;
    const int tk = blk*4 + wv;
    const float* xp = x + (size_t)tk*DDIM + lane*16;
    float xv[16];
    #pragma unroll
    for (int j=0;j<16;j+=4){ const float4 f=*(const float4*)(xp+j); xv[j]=f.x; xv[j+1]=f.y; xv[j+2]=f.z; xv[j+3]=f.w; }
    float s=0.f, q=0.f;
    #pragma unroll
    for (int j=0;j<16;++j){ s += xv[j]; q += xv[j]*xv[j]; }
    #pragma unroll
    for (int m=1;m<64;m<<=1){ s += __shfl_xor(s,m); q += __shfl_xor(q,m); }
    const float mu = s*(1.f/DDIM);
    const float rs = rsqrtf(q*(1.f/DDIM) - mu*mu + 1e-5f);
    #pragma unroll
    for (int j=0;j<16;j+=4){
      const float4 gg=*(const float4*)(g + lane*16 + j);
      const float4 bb=*(const float4*)(b + lane*16 + j);
      xv[j]   = (xv[j]  -mu)*rs*gg.x + bb.x;
      xv[j+1] = (xv[j+1]-mu)*rs*gg.y + bb.y;
      xv[j+2] = (xv[j+2]-mu)*rs*gg.z + bb.z;
      xv[j+3] = (xv[j+3]-mu)*rs*gg.w + bb.w;
    }
    f16x8 o0, o1;
    #pragma unroll
    for (int j=0;j<8;++j){ o0[j] = (f16)xv[j]; o1[j] = (f16)xv[8+j]; }
    *(f16x8*)(xn + (size_t)tk*DDIM + lane*16)     = o0;
    *(f16x8*)(xn + (size_t)tk*DDIM + lane*16 + 8) = o1;
    for (int e=0;e<32;++e){
      const int row = c_RROW[e];
      const float* rp = rw + (size_t)row*DDIM + lane*16;
      float d = 0.f;
      #pragma unroll
      for (int j=0;j<16;j+=4){
        const float4 f=*(const float4*)(rp+j);
        d += xv[j]*f.x + xv[j+1]*f.y + xv[j+2]*f.z + xv[j+3]*f.w;
      }
      #pragma unroll
      for (int m=1;m<64;m<<=1) d += __shfl_xor(d,m);
      if (lane==0) wsig[tk*32 + e] = 1.f/(1.f + expf(-(d + rb[row])));
    }
  } else if (blk < 4096){
    // W1 pack: c = v*32768 + wv*2048 + ic*64 + g4*16 + l15
    const int c = (blk-2048)*256 + tid;
    const int l15 = c & 15, g4 = (c>>4)&3, ic = (c>>6)&31, wvv = (c>>11)&15, v = c>>15;
    const float* s = w1 + (size_t)v*262144 + (size_t)(wvv*16+l15)*1024 + ic*32 + g4*8;
    const float4 a = *(const float4*)s, b4 = *(const float4*)(s+4);
    f16x8 o;
    o[0]=(f16)a.x; o[1]=(f16)a.y; o[2]=(f16)a.z; o[3]=(f16)a.w;
    o[4]=(f16)b4.x; o[5]=(f16)b4.y; o[6]=(f16)b4.z; o[7]=(f16)b4.w;
    *(f16x8*)(w1p + (size_t)c*8) = o;
  } else {
    // W2 pack: c = v*32768 + wv*2048 + ks*1024/4... c = v*32768 + wv*2048 + (ks*4+nf)*64 + g4*16 + l15
    const int c = (blk-4096)*256 + tid;
    const int l15 = c & 15, g4 = (c>>4)&3, nf = (c>>6)&3, ks = (c>>8)&7, wvv = (c>>11)&15, v = c>>15;
    const float* s = w2 + (size_t)v*262144 + (size_t)(wvv*64+nf*16+l15)*256 + ks*32 + g4*8;
    const float4 a = *(const float4*)s, b4 = *(const float4*)(s+4);
    f16x8 o;
    o[0]=(f16)a.x; o[1]=(f16)a.y; o[2]=(f16)a.z; o[3]=(f16)a.w;
    o[4]=(f16)b4.x; o[5]=(f16)b4.y; o[6]=(f16)b4.z; o[7]=(f16)b4.w;
    *(f16x8*)(w2p + (size_t)c*8) = o;
  }
}

// ---------------- kernel 2: fused persistent MoE-DAG ----------------
// 256 blocks x 1024 threads. All inter-node dataflow in 2 LDS ping-pong buffers
// (preds(v) ⊆ {v-1,v-2,0,1}); only O_0,O_1 touch global. Ain built in-place on O_{v-2}.
__global__ __launch_bounds__(1024,4) void k_moe(
    const f16* __restrict__ xn, const f16* __restrict__ w1p, const f16* __restrict__ w2p,
    const float* __restrict__ fc1b, const float* __restrict__ lng, const float* __restrict__ lnb,
    const float* __restrict__ f2bias, const float* __restrict__ wsigG,
    const float* __restrict__ x, float* __restrict__ out, f16* __restrict__ gouts)
{
  __shared__ float wsig[32][32];                 // router sigmoids [token][edge]
  __shared__ __align__(16) f16 Pbuf0[32*1032];   // ping-pong O_{v-1}/O_{v-2}+Ain, pad 1032
  __shared__ __align__(16) f16 Pbuf1[32*1032];
  __shared__ __align__(16) f16 hln[32*264];      // LN'd hidden [32][256] pad->264
  __shared__ float part[32][17][2];
  __shared__ float musq[32][2];

  const int tid = threadIdx.x;
  const int lane = tid & 63, wv = tid >> 6;      // wv 0..15
  const int l15 = lane & 15, g4 = (lane >> 4) & 3;
  const int blk = blockIdx.x, tok0 = blk * 32;
  const f32x4 fzero = {0.f,0.f,0.f,0.f};
  const int t0 = tid >> 7, cc8 = (tid & 127) * 8;   // chunk row base / col (f16)

  wsig[tid>>5][tid&31] = wsigG[tok0*32 + tid];

  f16* Pp = Pbuf0;   // holds O_{v-1} (garbage at v=0, unused)
  f16* Pc = Pbuf1;   // Ain target; holds O_{v-2} on entry (v>=2)

  for (int v=0; v<16; ++v){
    // ---- fc1 B prefetch (independent of stage) ----
    const f16* bp1 = w1p + (size_t)(v*16 + wv)*16384 + lane*8;
    f16x8 b1p[8];
    #pragma unroll
    for (int j=0;j<8;++j) b1p[j] = *(const f16x8*)(bp1 + j*512);

    // ---- stage: build Ain into Pc (in-place over O_{v-2}) ----
    if (v == 0){
      #pragma unroll
      for (int p=0;p<4;++p){
        const int t = t0 + p*8;
        *(f16x8*)&Pc[t*1032 + cc8] = *(const f16x8*)(xn + (size_t)(tok0+t)*DDIM + cc8);
      }
    } else {
      const int np = c_NP[v], off = c_OFF[v];
      const int ech = off + np - 1;        // chain edge (pred v-1)
      const int ev2 = off + np - 2;        // v-2 edge (valid if np>=2)
      const int nex = np - 2;              // extras: preds 0[,1] from gouts (v=14,15)
      f16x8 exv[2][4];
      #pragma unroll
      for (int i=0;i<2;++i) if (i<nex)
        #pragma unroll
        for (int p=0;p<4;++p){
          const int t = t0 + p*8;
          exv[i][p] = *(const f16x8*)(gouts + (size_t)i*TOKS*DDIM + (size_t)(tok0+t)*DDIM + cc8);
        }
      #pragma unroll
      for (int p=0;p<4;++p){
        const int t = t0 + p*8;
        const f16x8 pv = *(const f16x8*)&Pp[t*1032 + cc8];
        if (v <= 2)   // save O_0 (v=1) / O_1 (v=2) for nodes 14/15
          *(f16x8*)(gouts + (size_t)(v-1)*TOKS*DDIM + (size_t)(tok0+t)*DDIM + cc8) = pv;
        float f[8];
        const float wch = wsig[t][ech];
        #pragma unroll
        for (int j=0;j<8;++j) f[j] = wch*(float)pv[j];
        if (np >= 2){
          const f16x8 p2 = *(const f16x8*)&Pc[t*1032 + cc8];
          const float wv2 = wsig[t][ev2];
          #pragma unroll
          for (int j=0;j<8;++j) f[j] += wv2*(float)p2[j];
        }
        #pragma unroll
        for (int i=0;i<2;++i) if (i<nex){
          const float wx = wsig[t][off+i];
          #pragma unroll
          for (int j=0;j<8;++j) f[j] += wx*(float)exv[i][p][j];
        }
        f16x8 nv;
        #pragma unroll
        for (int j=0;j<8;++j) nv[j] = (f16)f[j];
        *(f16x8*)&Pc[t*1032 + cc8] = nv;
      }
    }
    __syncthreads();

    // ---- fc1: A from Pc (LDS), B prefetched stream ----
    f32x4 acc1[2] = {fzero, fzero};
    #pragma unroll
    for (int ic=0; ic<32; ++ic){
      const f16x8 b = b1p[ic&7];
      if (ic < 24) b1p[ic&7] = *(const f16x8*)(bp1 + (ic+8)*512);
      const f16x8 a0 = *(const f16x8*)&Pc[l15*1032      + ic*32 + g4*8];
      const f16x8 a1 = *(const f16x8*)&Pc[(16+l15)*1032 + ic*32 + g4*8];
      acc1[0] = __builtin_amdgcn_mfma_f32_16x16x32_f16(a0, b, acc1[0], 0,0,0);
      acc1[1] = __builtin_amdgcn_mfma_f32_16x16x32_f16(a1, b, acc1[1], 0,0,0);
    }

    // ---- fc2 B prefetch (hides under epilogue) ----
    const f16* bp2 = w2p + (size_t)(v*16 + wv)*16384 + lane*8;
    f16x8 b2p[8];
    #pragma unroll
    for (int j=0;j<8;++j) b2p[j] = *(const f16x8*)(bp2 + j*512);

    // ---- epilogue: bias + exact gelu + LN(256) ----
    const int c1 = wv*16 + l15;
    const float fb = fc1b[v*CHDIM + c1];
    const float lg = lng[v*CHDIM + c1], lb = lnb[v*CHDIM + c1];
    #pragma unroll
    for (int mf=0;mf<2;++mf)
      #pragma unroll
      for (int r=0;r<4;++r){
        const float h = acc1[mf][r] + fb;
        acc1[mf][r] = 0.5f*h*(1.f + erff(h*0.70710678118654752f));
      }
    #pragma unroll
    for (int mf=0;mf<2;++mf)
      #pragma unroll
      for (int r=0;r<4;++r){
        float s = acc1[mf][r], q = s*s;
        #pragma unroll
        for (int m=1;m<16;m<<=1){ s += __shfl_xor(s,m); q += __shfl_xor(q,m); }
        if (l15==0){ const int t = mf*16 + g4*4 + r; part[t][wv][0]=s; part[t][wv][1]=q; }
      }
    __syncthreads();
    if (tid < 32){
      float s=0.f, q=0.f;
      #pragma unroll
      for (int w=0;w<16;++w){ s += part[tid][w][0]; q += part[tid][w][1]; }
      const float mu = s*(1.f/CHDIM);
      musq[tid][0] = mu;
      musq[tid][1] = rsqrtf(q*(1.f/CHDIM) - mu*mu + 1e-5f);
    }
    __syncthreads();
    #pragma unroll
    for (int mf=0;mf<2;++mf)
      #pragma unroll
      for (int r=0;r<4;++r){
        const int t = mf*16 + g4*4 + r;
        hln[t*264 + c1] = (f16)((acc1[mf][r]-musq[t][0])*musq[t][1]*lg + lb);
      }
    __syncthreads();

    // ---- fc2: A from hln, B prefetched stream; writes O_v into Pc ----
    f32x4 acc2[2][4];
    #pragma unroll
    for (int mf=0;mf<2;++mf)
      #pragma unroll
      for (int nf=0;nf<4;++nf) acc2[mf][nf] = fzero;
    f16x8 a0h, a1h;
    #pragma unroll
    for (int i=0; i<32; ++i){
      const int ks = i>>2, nf = i&3;
      if (nf == 0){
        a0h = *(const f16x8*)&hln[l15*264      + ks*32 + g4*8];
        a1h = *(const f16x8*)&hln[(16+l15)*264 + ks*32 + g4*8];
      }
      const f16x8 b = b2p[i&7];
      if (i < 24) b2p[i&7] = *(const f16x8*)(bp2 + (i+8)*512);
      acc2[0][nf] = __builtin_amdgcn_mfma_f32_16x16x32_f16(a0h, b, acc2[0][nf], 0,0,0);
      acc2[1][nf] = __builtin_amdgcn_mfma_f32_16x16x32_f16(a1h, b, acc2[1][nf], 0,0,0);
    }
    #pragma unroll
    for (int mf=0;mf<2;++mf)
      #pragma unroll
      for (int nf=0;nf<4;++nf){
        const int c2 = wv*64 + nf*16 + l15;
        const float fb2 = (v==15) ? f2bias[c2] : 0.f;
        #pragma unroll
        for (int r=0;r<4;++r){
          const int t = mf*16 + g4*4 + r;
          Pc[t*1032 + c2] = (f16)(acc2[mf][nf][r] + fb2);
        }
      }
    __syncthreads();   // O_v visible before next stage / terminal write

    if (v == 15){
      #pragma unroll
      for (int p=0;p<4;++p){
        const int t = t0 + p*8;
        const f16x8 val = *(const f16x8*)&Pc[t*1032 + cc8];
        const size_t gi = (size_t)(tok0+t)*DDIM + cc8;
        const float4 x0 = *(const float4*)(x+gi), x1 = *(const float4*)(x+gi+4);
        float4 o0, o1;
        o0.x = x0.x + (float)val[0]; o0.y = x0.y + (float)val[1];
        o0.z = x0.z + (float)val[2]; o0.w = x0.w + (float)val[3];
        o1.x = x1.x + (float)val[4]; o1.y = x1.y + (float)val[5];
        o1.z = x1.z + (float)val[6]; o1.w = x1.w + (float)val[7];
        *(float4*)(out+gi) = o0; *(float4*)(out+gi+4) = o1;
      }
    }
    f16* tmp = Pp; Pp = Pc; Pc = tmp;   // rotate: Pc(O_v)->Pp ; Pp(O_{v-1})->Pc(=O_{v-2} next)
  }
}

extern "C" void kernel_launch(void* const* d_in, const int* in_sizes, int n_in,
                              void* d_out, int out_size, void* d_ws, size_t ws_size,
                              hipStream_t stream) {
  (void)in_sizes; (void)n_in; (void)out_size; (void)ws_size;
  const float* x   = (const float*)d_in[0];
  const float* ng  = (const float*)d_in[1];
  const float* nb_ = (const float*)d_in[2];
  const float* w1  = (const float*)d_in[3];
  const float* f1b = (const float*)d_in[4];
  const float* lg  = (const float*)d_in[5];
  const float* lb  = (const float*)d_in[6];
  const float* w2  = (const float*)d_in[7];
  const float* f2b = (const float*)d_in[8];
  const float* rw  = (const float*)d_in[9];
  const float* rb  = (const float*)d_in[10];
  float* out = (float*)d_out;

  char* ws = (char*)d_ws;
  f16*  xnh  = (f16*)(ws);                                   // 16 MB
  f16*  w1p  = (f16*)(ws + 16777216);                        //  8 MB
  f16*  w2p  = (f16*)(ws + 16777216 + 8388608);              //  8 MB
  float* wsg = (float*)(ws + 16777216 + 8388608 + 8388608);  //  1 MB
  f16*  gouts= (f16*)(ws + 16777216 + 8388608 + 8388608 + 1048576); // 32 MB (O_0, O_1)

  k_prep<<<6144, 256, 0, stream>>>(x, ng, nb_, xnh, rw, rb, wsg, w1, w2, w1p, w2p);
  k_moe<<<256, 1024, 0, stream>>>(xnh, w1p, w2p, f1b, lg, lb, f2b, wsg, x, out, gouts);
}